// Round 1
// baseline (920.821 us; speedup 1.0000x reference)
//
#include <hip/hip_runtime.h>

// Sub_MGU: B=64, T=2048, S=32 subunits, H=16.
// h_new[b,s,:] = f*n + (1-f)*h, per-subunit 16x16 recurrent mats.
// Parallelization: cell = (b,s) pair -> 2048 independent sequences.
// Wave (64 lanes) = 4 cells (same b, consecutive s); lane (sl, j) owns
// h[j] of cell sl and weight rows W_hhf[s][j][:], W_hhn[s][j][:] in VGPRs.
// Per-step h exchange via LDS (1 ds_write_b32 + 4 ds_read_b128, wave-internal,
// no barrier needed — LDS pipe is in-order per wave).

#define TT 2048
#define SS 32
#define HH 16
#define BB 64

__global__ __launch_bounds__(64) void mgu_kernel(
    const float* __restrict__ input,   // [B, T, S]
    const float* __restrict__ W_hif,   // [S, H]
    const float* __restrict__ W_hin,   // [S, H]
    const float* __restrict__ W_hhf,   // [S, H, H]
    const float* __restrict__ W_hhn,   // [S, H, H]
    const float* __restrict__ bias_hi, // [2*S*H]
    const float* __restrict__ bias_hh, // [2*S*H]
    float* __restrict__ out)           // [B, T, S*H]
{
    const int lane = threadIdx.x;      // 0..63
    const int sl   = lane >> 4;        // cell within wave (0..3)
    const int j    = lane & 15;        // output element within cell
    const int b    = blockIdx.x >> 3;  // batch index (0..63)
    const int sg   = blockIdx.x & 7;   // subunit group (0..7)
    const int s    = sg * 4 + sl;      // subunit (0..31)

    const int row = s * HH + j;        // row index into [S*H]-shaped params

    // ---- preload weights into registers (one-time) ----
    float wf[16], wn[16];
    {
        const float4* Wf4 = (const float4*)W_hhf + row * 4;
        const float4* Wn4 = (const float4*)W_hhn + row * 4;
#pragma unroll
        for (int q = 0; q < 4; ++q) {
            float4 a = Wf4[q];
            wf[4*q+0] = a.x; wf[4*q+1] = a.y; wf[4*q+2] = a.z; wf[4*q+3] = a.w;
            float4 c = Wn4[q];
            wn[4*q+0] = c.x; wn[4*q+1] = c.y; wn[4*q+2] = c.z; wn[4*q+3] = c.w;
        }
    }
    const float wif  = W_hif[row];
    const float win  = W_hin[row];
    // forget-gate biases always summed: fold b_if + b_hf
    const float bf   = bias_hi[row] + bias_hh[row];
    const float bin  = bias_hi[SS * HH + row];
    const float bhn  = bias_hh[SS * HH + row];

    __shared__ float hsh[64];

    const float* xp = input + (size_t)b * (TT * SS) + s;
    float*       op = out   + (size_t)b * (TT * SS * HH) + sg * 64 + lane;

    const float LOG2E  = 1.442695041f;   // sigmoid: 1/(1+2^(-x*log2e))
    const float TLOG2E = 2.885390082f;   // tanh:    1-2/(1+2^(2y*log2e))

    float h = 0.0f;
    float x = xp[0];                     // prefetch t=0

#pragma unroll 1
    for (int t = 0; t < TT; ++t) {
        // prefetch next step's input (clamped at the tail; harmless reload)
        const int tn = (t + 1 < TT) ? (t + 1) : t;
        const float xn = xp[tn * SS];

        // ---- wave-internal h exchange through LDS ----
        __builtin_amdgcn_wave_barrier();
        hsh[lane] = h;
        __builtin_amdgcn_wave_barrier();
        float hv[16];
        {
            const float4* hp = (const float4*)hsh + sl * 4;
            float4 h0 = hp[0], h1 = hp[1], h2 = hp[2], h3 = hp[3];
            hv[0]=h0.x;  hv[1]=h0.y;  hv[2]=h0.z;  hv[3]=h0.w;
            hv[4]=h1.x;  hv[5]=h1.y;  hv[6]=h1.z;  hv[7]=h1.w;
            hv[8]=h2.x;  hv[9]=h2.y;  hv[10]=h2.z; hv[11]=h2.w;
            hv[12]=h3.x; hv[13]=h3.y; hv[14]=h3.z; hv[15]=h3.w;
        }

        // ---- dual 16-deep dot products (f and n recurrent matvecs) ----
        float accf = __builtin_fmaf(x, wif, bf);  // i_f + folded biases
        float accn = bhn;                          // W_hhn . h + b_hn
#pragma unroll
        for (int k = 0; k < 16; ++k) {
            accf = __builtin_fmaf(wf[k], hv[k], accf);
            accn = __builtin_fmaf(wn[k], hv[k], accn);
        }

        // f = sigmoid(accf)
        const float f = __builtin_amdgcn_rcpf(
            1.0f + __builtin_amdgcn_exp2f(-LOG2E * accf));
        // n = tanh(i_n + f * (W_hhn.h + b_hn))
        const float i_n = __builtin_fmaf(x, win, bin);
        const float y   = __builtin_fmaf(f, accn, i_n);
        const float r = __builtin_amdgcn_rcpf(
            1.0f + __builtin_amdgcn_exp2f(TLOG2E * y));
        const float n = __builtin_fmaf(-2.0f, r, 1.0f);

        // h = f*n + (1-f)*h = h + f*(n-h)
        h = __builtin_fmaf(f, n - h, h);

        *op = h;
        op += SS * HH;   // advance one timestep in output
        x = xn;
    }
}

extern "C" void kernel_launch(void* const* d_in, const int* in_sizes, int n_in,
                              void* d_out, int out_size, void* d_ws, size_t ws_size,
                              hipStream_t stream) {
    const float* input   = (const float*)d_in[0];
    const float* W_hif   = (const float*)d_in[1];
    const float* W_hin   = (const float*)d_in[2];
    const float* W_hhf   = (const float*)d_in[3];
    const float* W_hhn   = (const float*)d_in[4];
    const float* bias_hi = (const float*)d_in[5];
    const float* bias_hh = (const float*)d_in[6];
    float* out = (float*)d_out;

    // 512 blocks x 64 threads = 2048 cells x 16 lanes
    mgu_kernel<<<dim3(512), dim3(64), 0, stream>>>(
        input, W_hif, W_hin, W_hhf, W_hhn, bias_hi, bias_hh, out);
}

// Round 3
// 676.671 us; speedup vs baseline: 1.3608x; 1.3608x over previous
//
#include <hip/hip_runtime.h>

// Sub_MGU: B=64, T=2048, S=32, H=16. 2048 independent serial sequences.
// Wave = 4 cells (same b, 4 consecutive s); lane (sl,j) owns h[j] and weight
// rows W_hhf/W_hhn[s][j][:] in VGPRs.
// R1/R2 changes vs R0 (latency-bound at ~823 cyc/step):
//  - x prefetched 8 steps deep in a register ring (was 1 step -> ate ~900cyc
//    HBM latency every step).
//  - h exchange via 16x ds_swizzle_b32 broadcast (was ds_write+barrier+
//    ds_read_b128 = 2 serialized LDS round-trips). R2: swizzle pattern must
//    be an ICE -> template-recursive instantiation.
//  - dot products split into even/odd chains (8-deep latency).
//  - block mapping b=idx&63 so same-b blocks co-locate per XCD L2.

#define TT 2048
#define SS 32
#define HH 16

// Broadcast h of lane ((lane&0x10)|K) within each 32-lane half:
// BitMode offset = (xor<<10)|(or<<5)|and = (K<<5)|0x10.
template <int K>
__device__ __forceinline__ void swz_bcast(int hi, float* hv) {
    hv[K] = __int_as_float(__builtin_amdgcn_ds_swizzle(hi, (K << 5) | 0x10));
    if constexpr (K + 1 < 16) swz_bcast<K + 1>(hi, hv);
}

__global__ __launch_bounds__(64) void mgu_kernel(
    const float* __restrict__ input,   // [B, T, S]
    const float* __restrict__ W_hif,   // [S, H]
    const float* __restrict__ W_hin,   // [S, H]
    const float* __restrict__ W_hhf,   // [S, H, H]
    const float* __restrict__ W_hhn,   // [S, H, H]
    const float* __restrict__ bias_hi, // [2*S*H]
    const float* __restrict__ bias_hh, // [2*S*H]
    float* __restrict__ out)           // [B, T, S*H]
{
    const int lane = threadIdx.x;      // 0..63
    const int sl   = lane >> 4;        // cell within wave (0..3)
    const int b    = blockIdx.x & 63;  // batch index — same-b blocks adjacent -> XCD L2 co-location
    const int sg   = blockIdx.x >> 6;  // subunit group (0..7)
    const int s    = sg * 4 + sl;      // subunit (0..31)
    const int j    = lane & 15;
    const int row  = s * HH + j;

    // ---- preload weights into registers ----
    float wf[16], wn[16];
    {
        const float4* Wf4 = (const float4*)W_hhf + row * 4;
        const float4* Wn4 = (const float4*)W_hhn + row * 4;
#pragma unroll
        for (int q = 0; q < 4; ++q) {
            float4 a = Wf4[q];
            wf[4*q+0] = a.x; wf[4*q+1] = a.y; wf[4*q+2] = a.z; wf[4*q+3] = a.w;
            float4 c = Wn4[q];
            wn[4*q+0] = c.x; wn[4*q+1] = c.y; wn[4*q+2] = c.z; wn[4*q+3] = c.w;
        }
    }
    const float wif = W_hif[row];
    const float win = W_hin[row];
    const float bf  = bias_hi[row] + bias_hh[row];          // folded forget biases
    const float bin = bias_hi[SS * HH + row];
    const float bhn = bias_hh[SS * HH + row];

    const float* xp = input + (size_t)b * (TT * SS) + s;
    float*       op = out   + (size_t)b * (TT * SS * HH) + sg * 64 + lane;

    const float LOG2E  = 1.442695041f;
    const float TLOG2E = 2.885390082f;

    // ---- 8-deep x prefetch ring (covers ~1600 cyc > HBM latency) ----
    float xbuf[8];
#pragma unroll
    for (int i = 0; i < 8; ++i) xbuf[i] = xp[i * SS];

    float h = 0.0f;

#pragma unroll 1
    for (int t = 0; t < TT; t += 8) {
#pragma unroll
        for (int p = 0; p < 8; ++p) {
            const float x = xbuf[p];
            // refill slot p for step t+p+8 (clamped tail; harmless reload)
            int tf = t + p + 8; tf = (tf < TT) ? tf : (TT - 1);
            xbuf[p] = xp[(size_t)tf * SS];

            // ---- h exchange: 16x ds_swizzle broadcast within 16-lane group
            float hv[16];
            swz_bcast<0>(__float_as_int(h), hv);

            // ---- dual matvecs, even/odd split: 4 independent 8-deep chains
            float accf0 = __builtin_fmaf(x, wif, bf), accf1 = 0.0f;
            float accn0 = bhn,                        accn1 = 0.0f;
#pragma unroll
            for (int k = 0; k < 8; ++k) {
                accf0 = __builtin_fmaf(wf[2*k],   hv[2*k],   accf0);
                accf1 = __builtin_fmaf(wf[2*k+1], hv[2*k+1], accf1);
                accn0 = __builtin_fmaf(wn[2*k],   hv[2*k],   accn0);
                accn1 = __builtin_fmaf(wn[2*k+1], hv[2*k+1], accn1);
            }
            const float accf = accf0 + accf1;
            const float accn = accn0 + accn1;

            // f = sigmoid(accf); n = tanh(i_n + f*accn)
            const float f = __builtin_amdgcn_rcpf(
                1.0f + __builtin_amdgcn_exp2f(-LOG2E * accf));
            const float i_n = __builtin_fmaf(x, win, bin);
            const float y   = __builtin_fmaf(f, accn, i_n);
            const float r = __builtin_amdgcn_rcpf(
                1.0f + __builtin_amdgcn_exp2f(TLOG2E * y));
            const float n = __builtin_fmaf(-2.0f, r, 1.0f);

            // h = h + f*(n-h)
            h = __builtin_fmaf(f, n - h, h);

            op[(size_t)(t + p) * (SS * HH)] = h;
        }
    }
}

extern "C" void kernel_launch(void* const* d_in, const int* in_sizes, int n_in,
                              void* d_out, int out_size, void* d_ws, size_t ws_size,
                              hipStream_t stream) {
    const float* input   = (const float*)d_in[0];
    const float* W_hif   = (const float*)d_in[1];
    const float* W_hin   = (const float*)d_in[2];
    const float* W_hhf   = (const float*)d_in[3];
    const float* W_hhn   = (const float*)d_in[4];
    const float* bias_hi = (const float*)d_in[5];
    const float* bias_hh = (const float*)d_in[6];
    float* out = (float*)d_out;

    mgu_kernel<<<dim3(512), dim3(64), 0, stream>>>(
        input, W_hif, W_hin, W_hhf, W_hhn, bias_hi, bias_hh, out);
}